// Round 13
// baseline (28.703 us; speedup 1.0000x reference)
//
#include <hip/hip_runtime.h>
#include <math.h>

#define HWSZ   784    // 28*28
#define NCH    2048
#define NB     16
#define NWIN   1595   // 625 + 529 + 441
#define NF4    196    // 784/4
#define NCHUNK 16
#define CC     128    // 2048/16

typedef float v4f __attribute__((ext_vector_type(4)));

// ---------------- Kernel 1: per-chunk channel sums (R12, best-known) ----------------
__global__ __launch_bounds__(256) void k_chan_partial(const float* __restrict__ in,
                                                      float* __restrict__ partial) {
    int chunk = blockIdx.x;
    int b     = blockIdx.y;
    int t     = threadIdx.x;
    if (t >= NF4) return;
    const v4f* p = reinterpret_cast<const v4f*>(
        in + ((size_t)b * NCH + (size_t)chunk * CC) * HWSZ) + t;
    v4f a0 = {0.f, 0.f, 0.f, 0.f};
    v4f a1 = {0.f, 0.f, 0.f, 0.f};
#pragma unroll 16
    for (int c = 0; c < CC; c += 2) {
        v4f v = __builtin_nontemporal_load(p + (size_t)c * NF4);
        v4f w = __builtin_nontemporal_load(p + (size_t)(c + 1) * NF4);
        a0 += v;
        a1 += w;
    }
    v4f acc = a0 + a1;
    reinterpret_cast<v4f*>(partial + ((size_t)b * NCHUNK + chunk) * HWSZ)[t] = acc;
}

// ---------------- Kernel 2: one block per batch; reduce once, pool all groups, 3 NMS waves ----------------
__global__ __launch_bounds__(256) void k_fused(const float* __restrict__ partial,
                                               float* __restrict__ out) {
    __shared__ float xs[HWSZ];
    __shared__ float rs[1932];   // rowsums: g0 [0,700) g1 [700,1344) g2 [1344,1932)
    __shared__ float sc[NWIN];
    int b = blockIdx.x;
    int t = threadIdx.x;

    // --- reduce 16 partials -> xs (single pass, 50KB) ---
    if (t < NF4) {
        float4 acc = make_float4(0.f, 0.f, 0.f, 0.f);
#pragma unroll 16
        for (int ch = 0; ch < NCHUNK; ++ch) {
            float4 v = reinterpret_cast<const float4*>(
                partial + ((size_t)b * NCHUNK + ch) * HWSZ)[t];
            acc.x += v.x; acc.y += v.y; acc.z += v.z; acc.w += v.w;
        }
        reinterpret_cast<float4*>(xs)[t] = acc;
    }
    __syncthreads();

    // --- all-group row sliding sums, flattened (1932 entries) ---
    for (int idx = t; idx < 1932; idx += 256) {
        int k, n, loc;
        if (idx < 700)       { k = 4; n = 25; loc = idx; }
        else if (idx < 1344) { k = 6; n = 23; loc = idx - 700; }
        else                 { k = 8; n = 21; loc = idx - 1344; }
        int row = loc / n, j = loc % n;
        const float* xr = xs + row * 28 + j;
        float s = 0.f;
        for (int dj = 0; dj < k; ++dj) s += xr[dj];
        rs[idx] = s;
    }
    __syncthreads();

    // --- all-group windows, flattened (1595) ---
    float* out_win = out + 192;
    for (int w = t; w < NWIN; w += 256) {
        int k, n, rbase, loc;
        float inv;
        if (w < 625)       { k = 4; n = 25; rbase = 0;    loc = w;        inv = 1.f / 16.f; }
        else if (w < 1154) { k = 6; n = 23; rbase = 700;  loc = w - 625;  inv = 1.f / 36.f; }
        else               { k = 8; n = 21; rbase = 1344; loc = w - 1154; inv = 1.f / 64.f; }
        int i = loc / n, j = loc % n;
        const float* rp = rs + rbase + i * n + j;
        float s = 0.f;
        for (int di = 0; di < k; ++di) s += rp[di * n];
        s *= inv;
        sc[w] = s;
        out_win[(size_t)b * NWIN + w] = s;
    }
    __syncthreads();

    // --- NMS: wave g handles group g, fully in registers ---
    int wave = t >> 6, lane = t & 63;
    if (wave < 3) {
        const int kArr[3]    = {4, 6, 8};
        const int nArr[3]    = {25, 23, 21};
        const int baseArr[3] = {0, 625, 1154};
        const int pickArr[3] = {3, 2, 1};
        const int offArr[3]  = {0, 3, 5};
        int k = kArr[wave], n = nArr[wave], base = baseArr[wave];
        int npick = pickArr[wave], off = offArr[wave];
        int cnt = n * n;           // <= 625 -> <= 10 slots/lane
        int kk2 = 2 * k * k;

        float s[10];
#pragma unroll
        for (int j = 0; j < 10; ++j) {
            int w = lane + 64 * j;
            s[j] = (w < cnt) ? sc[base + w] : -INFINITY;
        }

        for (int r = 0; r < npick; ++r) {
            // lane-local argmax (max score, tie -> smallest window index)
            float bs = -INFINITY;
            int   bi = 1 << 30;
#pragma unroll
            for (int j = 0; j < 10; ++j) {
                int w = lane + 64 * j;
                float v = s[j];
                if (v > bs || (v == bs && w < bi)) { bs = v; bi = w; }
            }
            // wave butterfly reduce
#pragma unroll
            for (int m = 1; m < 64; m <<= 1) {
                float os = __shfl_xor(bs, m);
                int   oi = __shfl_xor(bi, m);
                if (os > bs || (os == bs && oi < bi)) { bs = os; bi = oi; }
            }
            if (lane == 0) {
                out[(size_t)b * 6 + off + r]      = (float)(base + bi);
                out[96 + (size_t)b * 6 + off + r] = bs;
            }
            // suppress: IoU > 0.25  <=>  5*inter > 2*k*k (same-size boxes, exact int test)
            int pi = bi / n, pj = bi % n;
#pragma unroll
            for (int j = 0; j < 10; ++j) {
                int w = lane + 64 * j;
                int i  = w / n, jj = w % n;
                int di = i - pi;  if (di < 0) di = -di;
                int dj = jj - pj; if (dj < 0) dj = -dj;
                int iw = k - dj, ih = k - di;
                int inter = (iw > 0 && ih > 0) ? iw * ih : 0;
                if (5 * inter > kk2) s[j] = -INFINITY;
            }
        }
    }
}

extern "C" void kernel_launch(void* const* d_in, const int* in_sizes, int n_in,
                              void* d_out, int out_size, void* d_ws, size_t ws_size,
                              hipStream_t stream) {
    // input order: num_proposals, input_tensor, window_nums_sum, N_list, iou_thresholds, coordinates_cat
    const float* in = (const float*)d_in[1];
    float* out = (float*)d_out;
    float* part = (float*)d_ws;   // 16*16*784 floats = 0.8 MB

    dim3 g1(NCHUNK, NB);
    k_chan_partial<<<g1, 256, 0, stream>>>(in, part);
    k_fused<<<NB, 256, 0, stream>>>(part, out);
}

// Round 14
// 27.815 us; speedup vs baseline: 1.0319x; 1.0319x over previous
//
#include <hip/hip_runtime.h>
#include <math.h>

#define HWSZ   784    // 28*28
#define NCH    2048
#define NB     16
#define NWIN   1595   // 625 + 529 + 441
#define NF4    196    // 784/4
#define NCHUNK 16
#define CC     128    // 2048/16

typedef float v4f __attribute__((ext_vector_type(4)));

// ---------------- Kernel 1: per-chunk channel sums (R12, best-known) ----------------
// 256 blocks = 1/CU, each streams a contiguous 400KB region; nt loads; 2 chains.
__global__ __launch_bounds__(256) void k_chan_partial(const float* __restrict__ in,
                                                      float* __restrict__ partial) {
    int chunk = blockIdx.x;
    int b     = blockIdx.y;
    int t     = threadIdx.x;
    if (t >= NF4) return;
    const v4f* p = reinterpret_cast<const v4f*>(
        in + ((size_t)b * NCH + (size_t)chunk * CC) * HWSZ) + t;
    v4f a0 = {0.f, 0.f, 0.f, 0.f};
    v4f a1 = {0.f, 0.f, 0.f, 0.f};
#pragma unroll 16
    for (int c = 0; c < CC; c += 2) {
        v4f v = __builtin_nontemporal_load(p + (size_t)c * NF4);
        v4f w = __builtin_nontemporal_load(p + (size_t)(c + 1) * NF4);
        a0 += v;
        a1 += w;
    }
    v4f acc = a0 + a1;
    reinterpret_cast<v4f*>(partial + ((size_t)b * NCHUNK + chunk) * HWSZ)[t] = acc;
}

// ---------------- Kernel 2: per-(group,batch) reduce + separable pool + NMS ----------------
// grid (3, NB); each block re-reduces partials (L2/L3-hit) then handles only its group.
__global__ __launch_bounds__(256) void k_fused(const float* __restrict__ partial,
                                               float* __restrict__ out) {
    __shared__ float xs[HWSZ];
    __shared__ float rowsum[28 * 25];   // 28 rows x n cols (n<=25)
    __shared__ float sc[625];
    int g = blockIdx.x;
    int b = blockIdx.y;
    int t = threadIdx.x;

    const int kArr[3]    = {4, 6, 8};
    const int nArr[3]    = {25, 23, 21};
    const int baseArr[3] = {0, 625, 1154};
    const int pickArr[3] = {3, 2, 1};
    const int offArr[3]  = {0, 3, 5};
    int k = kArr[g], n = nArr[g], base = baseArr[g];
    int cnt = n * n;

    // --- reduce partials -> xs ---
    if (t < NF4) {
        float4 acc = make_float4(0.f, 0.f, 0.f, 0.f);
#pragma unroll 16
        for (int ch = 0; ch < NCHUNK; ++ch) {
            float4 v = reinterpret_cast<const float4*>(
                partial + ((size_t)b * NCHUNK + ch) * HWSZ)[t];
            acc.x += v.x; acc.y += v.y; acc.z += v.z; acc.w += v.w;
        }
        reinterpret_cast<float4*>(xs)[t] = acc;
    }
    __syncthreads();

    // --- per-row sliding sums: rowsum[row*n + j] = sum_{dj<k} xs[row*28 + j+dj] ---
    int nrs = 28 * n;
    for (int idx = t; idx < nrs; idx += 256) {
        int row = idx / n, j = idx % n;
        const float* xr = xs + row * 28 + j;
        float s = 0.f;
        for (int dj = 0; dj < k; ++dj) s += xr[dj];
        rowsum[idx] = s;
    }
    __syncthreads();

    // --- windows: k adds of rowsums; write LDS copy + global window_scores ---
    float* out_win = out + 192;
    float inv = 1.f / (float)(k * k);
    for (int w = t; w < cnt; w += 256) {
        int i = w / n, j = w % n;
        const float* rp = rowsum + i * n + j;
        float s = 0.f;
        for (int di = 0; di < k; ++di) s += rp[di * n];
        s *= inv;
        sc[w] = s;
        out_win[(size_t)b * NWIN + base + w] = s;
    }
    __syncthreads();

    // --- NMS: wave 0, fully in registers ---
    if (t < 64) {
        int lane = t;
        int npick = pickArr[g], off = offArr[g];
        int kk2 = 2 * k * k;

        float s[10];
#pragma unroll
        for (int j = 0; j < 10; ++j) {
            int w = lane + 64 * j;
            s[j] = (w < cnt) ? sc[w] : -INFINITY;
        }

        for (int r = 0; r < npick; ++r) {
            // lane-local argmax (max score, tie -> smallest window index)
            float bs = -INFINITY;
            int   bi = 1 << 30;
#pragma unroll
            for (int j = 0; j < 10; ++j) {
                int w = lane + 64 * j;
                float v = s[j];
                if (v > bs || (v == bs && w < bi)) { bs = v; bi = w; }
            }
            // wave butterfly reduce
#pragma unroll
            for (int m = 1; m < 64; m <<= 1) {
                float os = __shfl_xor(bs, m);
                int   oi = __shfl_xor(bi, m);
                if (os > bs || (os == bs && oi < bi)) { bs = os; bi = oi; }
            }
            if (lane == 0) {
                out[(size_t)b * 6 + off + r]      = (float)(base + bi);
                out[96 + (size_t)b * 6 + off + r] = bs;
            }
            // suppress: IoU > 0.25  <=>  5*inter > 2*k*k (same-size boxes, exact int test)
            int pi = bi / n, pj = bi % n;
#pragma unroll
            for (int j = 0; j < 10; ++j) {
                int w = lane + 64 * j;
                int i  = w / n, jj = w % n;
                int di = i - pi;  if (di < 0) di = -di;
                int dj = jj - pj; if (dj < 0) dj = -dj;
                int iw = k - dj, ih = k - di;
                int inter = (iw > 0 && ih > 0) ? iw * ih : 0;
                if (5 * inter > kk2) s[j] = -INFINITY;
            }
        }
    }
}

extern "C" void kernel_launch(void* const* d_in, const int* in_sizes, int n_in,
                              void* d_out, int out_size, void* d_ws, size_t ws_size,
                              hipStream_t stream) {
    // input order: num_proposals, input_tensor, window_nums_sum, N_list, iou_thresholds, coordinates_cat
    const float* in = (const float*)d_in[1];
    float* out = (float*)d_out;
    float* part = (float*)d_ws;   // 16*16*784 floats = 0.8 MB

    dim3 g1(NCHUNK, NB);
    k_chan_partial<<<g1, 256, 0, stream>>>(in, part);
    dim3 g2(3, NB);
    k_fused<<<g2, 256, 0, stream>>>(part, out);
}